// Round 1
// baseline (1371.361 us; speedup 1.0000x reference)
//
#include <hip/hip_runtime.h>
#include <math.h>

#define N_NODES 100000
#define N_EDGES 600000

// ---------------------------------------------------------------------------
// Edge aggregation: agg[dst] += relu(x[src] + edge_feats @ We + be)
// thread c in [0,128) handles feature c; 2 edges per 256-thread block-iter.
// We column (32 floats) cached in registers; ef row broadcast via float4.
// ---------------------------------------------------------------------------
__global__ __launch_bounds__(256) void edge_agg_k(
    const float* __restrict__ x, const int* __restrict__ src, const int* __restrict__ dst,
    const float* __restrict__ ef, const float* __restrict__ We, const float* __restrict__ be,
    float* __restrict__ agg)
{
    const int c  = threadIdx.x & 127;   // feature
    const int eo = threadIdx.x >> 7;    // edge slot 0/1
    float we[32];
#pragma unroll
    for (int d = 0; d < 32; ++d) we[d] = We[d * 128 + c];
    const float bec = be[c];

    const int estride = gridDim.x * 2;
    for (int e = blockIdx.x * 2 + eo; e < N_EDGES; e += estride) {
        const int s = src[e];
        const int t = dst[e];
        float acc = bec;
        const float4* ef4 = (const float4*)(ef + (size_t)e * 32);
#pragma unroll
        for (int d4 = 0; d4 < 8; ++d4) {
            float4 v = ef4[d4];
            acc = fmaf(v.x, we[4 * d4 + 0], acc);
            acc = fmaf(v.y, we[4 * d4 + 1], acc);
            acc = fmaf(v.z, we[4 * d4 + 2], acc);
            acc = fmaf(v.w, we[4 * d4 + 3], acc);
        }
        float msg = x[(size_t)s * 128 + c] + acc;
        msg = fmaxf(msg, 0.0f);
        atomicAdd(&agg[(size_t)t * 128 + c], msg);
    }
}

// ---------------------------------------------------------------------------
// Fused 2-layer node MLP:
//   h   = xin (+ agg)                              [64-node tile]
//   t   = act1(h @ Wa + ba)        act1 = relu (conv) or tanh (head)
//   out = actF(t @ Wb + bb)        actF = tanh (conv) or identity (head)
// Input tile staged transposed (k-major) in LDS; layer-A accumulators for both
// 64-wide output halves held in registers so t overwrites the same LDS buffer.
// 4x4 microtile per thread; weights streamed from global (L1/L2 resident).
// ---------------------------------------------------------------------------
template <int NOUT, bool TANH1, bool TANHF, bool ADDAGG>
__global__ __launch_bounds__(256, 4) void mlp2_k(
    const float* __restrict__ xin, const float* __restrict__ agg,
    const float* __restrict__ Wa, const float* __restrict__ ba,
    const float* __restrict__ Wb, const float* __restrict__ bb,
    float* __restrict__ out)
{
    __shared__ float hT[128][68];   // [k][m], pad 68 keeps float4 alignment, 4-way-ish conflicts
    const int tid = threadIdx.x;
    const int n0  = blockIdx.x * 64;

    // ---- load + transpose: 64 rows x 128 features ----
    {
        const int mrow = tid >> 5;   // 0..7
        const int kq   = tid & 31;   // float4 column
#pragma unroll
        for (int g = 0; g < 8; ++g) {
            const int row  = g * 8 + mrow;
            const int node = n0 + row;
            float4 v = make_float4(0.f, 0.f, 0.f, 0.f);
            if (node < N_NODES) {
                v = *(const float4*)(xin + (size_t)node * 128 + kq * 4);
                if (ADDAGG) {
                    float4 a = *(const float4*)(agg + (size_t)node * 128 + kq * 4);
                    v.x += a.x; v.y += a.y; v.z += a.z; v.w += a.w;
                }
            }
            hT[kq * 4 + 0][row] = v.x;
            hT[kq * 4 + 1][row] = v.y;
            hT[kq * 4 + 2][row] = v.z;
            hT[kq * 4 + 3][row] = v.w;
        }
    }
    __syncthreads();

    const int ty4 = (tid >> 4) * 4;   // node offset within tile
    const int tx4 = (tid & 15) * 4;   // feature offset within 64-group

    // ---- layer A: both 64-wide halves, accumulators in registers ----
    float acc[2][4][4];
#pragma unroll
    for (int p = 0; p < 2; ++p)
#pragma unroll
        for (int i = 0; i < 4; ++i)
#pragma unroll
            for (int j = 0; j < 4; ++j) acc[p][i][j] = 0.f;

#pragma unroll 4
    for (int k = 0; k < 128; ++k) {
        const float4 av = *(const float4*)&hT[k][ty4];
#pragma unroll
        for (int p = 0; p < 2; ++p) {
            const float4 bv = *(const float4*)(Wa + (size_t)k * 128 + p * 64 + tx4);
            acc[p][0][0] = fmaf(av.x, bv.x, acc[p][0][0]);
            acc[p][0][1] = fmaf(av.x, bv.y, acc[p][0][1]);
            acc[p][0][2] = fmaf(av.x, bv.z, acc[p][0][2]);
            acc[p][0][3] = fmaf(av.x, bv.w, acc[p][0][3]);
            acc[p][1][0] = fmaf(av.y, bv.x, acc[p][1][0]);
            acc[p][1][1] = fmaf(av.y, bv.y, acc[p][1][1]);
            acc[p][1][2] = fmaf(av.y, bv.z, acc[p][1][2]);
            acc[p][1][3] = fmaf(av.y, bv.w, acc[p][1][3]);
            acc[p][2][0] = fmaf(av.z, bv.x, acc[p][2][0]);
            acc[p][2][1] = fmaf(av.z, bv.y, acc[p][2][1]);
            acc[p][2][2] = fmaf(av.z, bv.z, acc[p][2][2]);
            acc[p][2][3] = fmaf(av.z, bv.w, acc[p][2][3]);
            acc[p][3][0] = fmaf(av.w, bv.x, acc[p][3][0]);
            acc[p][3][1] = fmaf(av.w, bv.y, acc[p][3][1]);
            acc[p][3][2] = fmaf(av.w, bv.z, acc[p][3][2]);
            acc[p][3][3] = fmaf(av.w, bv.w, acc[p][3][3]);
        }
    }
    __syncthreads();   // all reads of hT done before overwrite

    // write t (transposed, k-major) back into hT
#pragma unroll
    for (int p = 0; p < 2; ++p) {
        const int cb = p * 64 + tx4;
        const float4 bias = *(const float4*)(ba + cb);
        const float bj[4] = {bias.x, bias.y, bias.z, bias.w};
#pragma unroll
        for (int i = 0; i < 4; ++i) {
#pragma unroll
            for (int j = 0; j < 4; ++j) {
                float v = acc[p][i][j] + bj[j];
                v = TANH1 ? tanhf(v) : fmaxf(v, 0.f);
                hT[cb + j][ty4 + i] = v;
            }
        }
    }
    __syncthreads();

    // ---- layer B ----
#pragma unroll
    for (int p = 0; p < NOUT / 64; ++p) {
        float a2[4][4];
#pragma unroll
        for (int i = 0; i < 4; ++i)
#pragma unroll
            for (int j = 0; j < 4; ++j) a2[i][j] = 0.f;

#pragma unroll 4
        for (int k = 0; k < 128; ++k) {
            const float4 av = *(const float4*)&hT[k][ty4];
            const float4 bv = *(const float4*)(Wb + (size_t)k * NOUT + p * 64 + tx4);
            a2[0][0] = fmaf(av.x, bv.x, a2[0][0]);
            a2[0][1] = fmaf(av.x, bv.y, a2[0][1]);
            a2[0][2] = fmaf(av.x, bv.z, a2[0][2]);
            a2[0][3] = fmaf(av.x, bv.w, a2[0][3]);
            a2[1][0] = fmaf(av.y, bv.x, a2[1][0]);
            a2[1][1] = fmaf(av.y, bv.y, a2[1][1]);
            a2[1][2] = fmaf(av.y, bv.z, a2[1][2]);
            a2[1][3] = fmaf(av.y, bv.w, a2[1][3]);
            a2[2][0] = fmaf(av.z, bv.x, a2[2][0]);
            a2[2][1] = fmaf(av.z, bv.y, a2[2][1]);
            a2[2][2] = fmaf(av.z, bv.z, a2[2][2]);
            a2[2][3] = fmaf(av.z, bv.w, a2[2][3]);
            a2[3][0] = fmaf(av.w, bv.x, a2[3][0]);
            a2[3][1] = fmaf(av.w, bv.y, a2[3][1]);
            a2[3][2] = fmaf(av.w, bv.z, a2[3][2]);
            a2[3][3] = fmaf(av.w, bv.w, a2[3][3]);
        }
        const int cb = p * 64 + tx4;
        const float4 bias = *(const float4*)(bb + cb);
#pragma unroll
        for (int i = 0; i < 4; ++i) {
            const int node = n0 + ty4 + i;
            if (node < N_NODES) {
                float4 o;
                o.x = a2[i][0] + bias.x;
                o.y = a2[i][1] + bias.y;
                o.z = a2[i][2] + bias.z;
                o.w = a2[i][3] + bias.w;
                if (TANHF) { o.x = tanhf(o.x); o.y = tanhf(o.y); o.z = tanhf(o.z); o.w = tanhf(o.w); }
                *(float4*)(out + (size_t)node * NOUT + cb) = o;
            }
        }
    }
}

// ---------------------------------------------------------------------------
extern "C" void kernel_launch(void* const* d_in, const int* in_sizes, int n_in,
                              void* d_out, int out_size, void* d_ws, size_t ws_size,
                              hipStream_t stream)
{
    const float* x   = (const float*)d_in[0];
    const int*   ei  = (const int*)  d_in[1];
    const float* ef  = (const float*)d_in[2];
    const float* We1 = (const float*)d_in[3];
    const float* be1 = (const float*)d_in[4];
    const float* W1a = (const float*)d_in[5];
    const float* b1a = (const float*)d_in[6];
    const float* W1b = (const float*)d_in[7];
    const float* b1b = (const float*)d_in[8];
    const float* We2 = (const float*)d_in[9];
    const float* be2 = (const float*)d_in[10];
    const float* W2a = (const float*)d_in[11];
    const float* b2a = (const float*)d_in[12];
    const float* W2b = (const float*)d_in[13];
    const float* b2b = (const float*)d_in[14];
    const float* Wf1 = (const float*)d_in[15];
    const float* bf1 = (const float*)d_in[16];
    const float* Wf2 = (const float*)d_in[17];
    const float* bf2 = (const float*)d_in[18];
    float* out = (float*)d_out;

    const int* src = ei;             // edge_index[0]
    const int* dst = ei + N_EDGES;   // edge_index[1]

    float* agg = (float*)d_ws;                       // [N,128] fp32
    float* h   = agg + (size_t)N_NODES * 128;        // [N,128] fp32
    const size_t aggBytes = (size_t)N_NODES * 128 * sizeof(float);

    const int mlpGrid  = (N_NODES + 63) / 64;
    const int edgeGrid = 2048;

    // ---- conv1 ----
    hipMemsetAsync(agg, 0, aggBytes, stream);
    edge_agg_k<<<edgeGrid, 256, 0, stream>>>(x, src, dst, ef, We1, be1, agg);
    mlp2_k<128, false, true, true><<<mlpGrid, 256, 0, stream>>>(x, agg, W1a, b1a, W1b, b1b, h);

    // ---- conv2 (h in-place is safe: each block consumes its rows into LDS first) ----
    hipMemsetAsync(agg, 0, aggBytes, stream);
    edge_agg_k<<<edgeGrid, 256, 0, stream>>>(h, src, dst, ef, We2, be2, agg);
    mlp2_k<128, false, true, true><<<mlpGrid, 256, 0, stream>>>(h, agg, W2a, b2a, W2b, b2b, h);

    // ---- head: tanh(h @ Wfc1 + bfc1) @ Wfc2 + bfc2 ----
    mlp2_k<64, true, false, false><<<mlpGrid, 256, 0, stream>>>(h, nullptr, Wf1, bf1, Wf2, bf2, out);
}

// Round 2
// 1310.742 us; speedup vs baseline: 1.0462x; 1.0462x over previous
//
#include <hip/hip_runtime.h>
#include <math.h>

#define N_NODES 100000
#define N_EDGES 600000
#define NB_SCAN ((N_NODES + 1023) / 1024)   // 98 scan blocks of 1024

// ===========================================================================
// CSR build: counting sort of edges by dst.
//   hist_k    : rank[e] = atomicAdd(counts[dst[e]], 1)   (int atomics, low contention)
//   scan_a/b/c: exclusive scan counts -> row_ptr (hierarchical, 1024/block)
//   scatter_k : perm[row_ptr[dst[e]] + rank[e]] = e
// edge_index is a fixed input, so the sort is identical every call.
// ===========================================================================
__global__ void hist_k(const int* __restrict__ dst, int* __restrict__ counts,
                       int* __restrict__ rank)
{
    int e = blockIdx.x * 256 + threadIdx.x;
    if (e < N_EDGES) rank[e] = atomicAdd(&counts[dst[e]], 1);
}

__global__ void scan_a_k(const int* __restrict__ counts, int* __restrict__ row_ptr,
                         int* __restrict__ blockSums)
{
    __shared__ int s[256];
    const int t = threadIdx.x;
    const int base = blockIdx.x * 1024 + t * 4;
    int c[4];
#pragma unroll
    for (int j = 0; j < 4; ++j) c[j] = (base + j < N_NODES) ? counts[base + j] : 0;
    const int tot = c[0] + c[1] + c[2] + c[3];
    s[t] = tot;
    __syncthreads();
    for (int off = 1; off < 256; off <<= 1) {
        int v = (t >= off) ? s[t - off] : 0;
        __syncthreads();
        s[t] += v;
        __syncthreads();
    }
    int run = s[t] - tot;   // exclusive offset of this thread within block
#pragma unroll
    for (int j = 0; j < 4; ++j) {
        if (base + j < N_NODES) row_ptr[base + j] = run;
        run += c[j];
    }
    if (t == 255) blockSums[blockIdx.x] = s[255];
}

__global__ void scan_b_k(const int* __restrict__ blockSums, int* __restrict__ blockOffs)
{
    if (threadIdx.x == 0) {
        int run = 0;
        for (int b = 0; b < NB_SCAN; ++b) { blockOffs[b] = run; run += blockSums[b]; }
    }
}

__global__ void scan_c_k(int* __restrict__ row_ptr, const int* __restrict__ blockOffs)
{
    int i = blockIdx.x * 256 + threadIdx.x;
    if (i < N_NODES) row_ptr[i] += blockOffs[i >> 10];
    if (i == 0) row_ptr[N_NODES] = N_EDGES;
}

__global__ void scatter_k(const int* __restrict__ dst, const int* __restrict__ row_ptr,
                          const int* __restrict__ rank, int* __restrict__ perm)
{
    int e = blockIdx.x * 256 + threadIdx.x;
    if (e < N_EDGES) perm[row_ptr[dst[e]] + rank[e]] = e;
}

// ===========================================================================
// CSR gather-aggregation: agg[n] = sum_{e in in(n)} relu(x[src[e]] + ef[e]@We + be)
// 128 threads per node (thread = feature), 2 nodes per 256-block.
// We column cached in 32 VGPRs; one coalesced 512B store per node; NO atomics.
// ===========================================================================
__global__ __launch_bounds__(256) void agg_csr_k(
    const float* __restrict__ x, const int* __restrict__ src, const float* __restrict__ ef,
    const int* __restrict__ row_ptr, const int* __restrict__ perm,
    const float* __restrict__ We, const float* __restrict__ be, float* __restrict__ agg)
{
    const int c    = threadIdx.x & 127;
    const int slot = threadIdx.x >> 7;
    const int node = blockIdx.x * 2 + slot;
    if (node >= N_NODES) return;

    float we[32];
#pragma unroll
    for (int d = 0; d < 32; ++d) we[d] = We[d * 128 + c];
    const float bec = be[c];

    const int start = row_ptr[node];
    const int end   = row_ptr[node + 1];
    float acc = 0.f;

    int e = (start < end) ? perm[start] : 0;
    for (int i = start; i < end; ++i) {
        const int s = src[e];
        const int e_nxt = (i + 1 < end) ? perm[i + 1] : 0;   // prefetch next edge id
        float ed = bec;
        const float4* ef4 = (const float4*)(ef + (size_t)e * 32);
#pragma unroll
        for (int d4 = 0; d4 < 8; ++d4) {
            float4 v = ef4[d4];
            ed = fmaf(v.x, we[4 * d4 + 0], ed);
            ed = fmaf(v.y, we[4 * d4 + 1], ed);
            ed = fmaf(v.z, we[4 * d4 + 2], ed);
            ed = fmaf(v.w, we[4 * d4 + 3], ed);
        }
        const float m = x[(size_t)s * 128 + c] + ed;
        acc += fmaxf(m, 0.f);
        e = e_nxt;
    }
    agg[(size_t)node * 128 + c] = acc;
}

// ---------------------------------------------------------------------------
// Fused 2-layer node MLP (unchanged from round 1):
//   t   = act1((xin + agg) @ Wa + ba);  out = actF(t @ Wb + bb)
// ---------------------------------------------------------------------------
template <int NOUT, bool TANH1, bool TANHF, bool ADDAGG>
__global__ __launch_bounds__(256, 4) void mlp2_k(
    const float* __restrict__ xin, const float* __restrict__ agg,
    const float* __restrict__ Wa, const float* __restrict__ ba,
    const float* __restrict__ Wb, const float* __restrict__ bb,
    float* __restrict__ out)
{
    __shared__ float hT[128][68];
    const int tid = threadIdx.x;
    const int n0  = blockIdx.x * 64;

    {
        const int mrow = tid >> 5;
        const int kq   = tid & 31;
#pragma unroll
        for (int g = 0; g < 8; ++g) {
            const int row  = g * 8 + mrow;
            const int node = n0 + row;
            float4 v = make_float4(0.f, 0.f, 0.f, 0.f);
            if (node < N_NODES) {
                v = *(const float4*)(xin + (size_t)node * 128 + kq * 4);
                if (ADDAGG) {
                    float4 a = *(const float4*)(agg + (size_t)node * 128 + kq * 4);
                    v.x += a.x; v.y += a.y; v.z += a.z; v.w += a.w;
                }
            }
            hT[kq * 4 + 0][row] = v.x;
            hT[kq * 4 + 1][row] = v.y;
            hT[kq * 4 + 2][row] = v.z;
            hT[kq * 4 + 3][row] = v.w;
        }
    }
    __syncthreads();

    const int ty4 = (tid >> 4) * 4;
    const int tx4 = (tid & 15) * 4;

    float acc[2][4][4];
#pragma unroll
    for (int p = 0; p < 2; ++p)
#pragma unroll
        for (int i = 0; i < 4; ++i)
#pragma unroll
            for (int j = 0; j < 4; ++j) acc[p][i][j] = 0.f;

#pragma unroll 4
    for (int k = 0; k < 128; ++k) {
        const float4 av = *(const float4*)&hT[k][ty4];
#pragma unroll
        for (int p = 0; p < 2; ++p) {
            const float4 bv = *(const float4*)(Wa + (size_t)k * 128 + p * 64 + tx4);
            acc[p][0][0] = fmaf(av.x, bv.x, acc[p][0][0]);
            acc[p][0][1] = fmaf(av.x, bv.y, acc[p][0][1]);
            acc[p][0][2] = fmaf(av.x, bv.z, acc[p][0][2]);
            acc[p][0][3] = fmaf(av.x, bv.w, acc[p][0][3]);
            acc[p][1][0] = fmaf(av.y, bv.x, acc[p][1][0]);
            acc[p][1][1] = fmaf(av.y, bv.y, acc[p][1][1]);
            acc[p][1][2] = fmaf(av.y, bv.z, acc[p][1][2]);
            acc[p][1][3] = fmaf(av.y, bv.w, acc[p][1][3]);
            acc[p][2][0] = fmaf(av.z, bv.x, acc[p][2][0]);
            acc[p][2][1] = fmaf(av.z, bv.y, acc[p][2][1]);
            acc[p][2][2] = fmaf(av.z, bv.z, acc[p][2][2]);
            acc[p][2][3] = fmaf(av.z, bv.w, acc[p][2][3]);
            acc[p][3][0] = fmaf(av.w, bv.x, acc[p][3][0]);
            acc[p][3][1] = fmaf(av.w, bv.y, acc[p][3][1]);
            acc[p][3][2] = fmaf(av.w, bv.z, acc[p][3][2]);
            acc[p][3][3] = fmaf(av.w, bv.w, acc[p][3][3]);
        }
    }
    __syncthreads();

#pragma unroll
    for (int p = 0; p < 2; ++p) {
        const int cb = p * 64 + tx4;
        const float4 bias = *(const float4*)(ba + cb);
        const float bj[4] = {bias.x, bias.y, bias.z, bias.w};
#pragma unroll
        for (int i = 0; i < 4; ++i) {
#pragma unroll
            for (int j = 0; j < 4; ++j) {
                float v = acc[p][i][j] + bj[j];
                v = TANH1 ? tanhf(v) : fmaxf(v, 0.f);
                hT[cb + j][ty4 + i] = v;
            }
        }
    }
    __syncthreads();

#pragma unroll
    for (int p = 0; p < NOUT / 64; ++p) {
        float a2[4][4];
#pragma unroll
        for (int i = 0; i < 4; ++i)
#pragma unroll
            for (int j = 0; j < 4; ++j) a2[i][j] = 0.f;

#pragma unroll 4
        for (int k = 0; k < 128; ++k) {
            const float4 av = *(const float4*)&hT[k][ty4];
            const float4 bv = *(const float4*)(Wb + (size_t)k * NOUT + p * 64 + tx4);
            a2[0][0] = fmaf(av.x, bv.x, a2[0][0]);
            a2[0][1] = fmaf(av.x, bv.y, a2[0][1]);
            a2[0][2] = fmaf(av.x, bv.z, a2[0][2]);
            a2[0][3] = fmaf(av.x, bv.w, a2[0][3]);
            a2[1][0] = fmaf(av.y, bv.x, a2[1][0]);
            a2[1][1] = fmaf(av.y, bv.y, a2[1][1]);
            a2[1][2] = fmaf(av.y, bv.z, a2[1][2]);
            a2[1][3] = fmaf(av.y, bv.w, a2[1][3]);
            a2[2][0] = fmaf(av.z, bv.x, a2[2][0]);
            a2[2][1] = fmaf(av.z, bv.y, a2[2][1]);
            a2[2][2] = fmaf(av.z, bv.z, a2[2][2]);
            a2[2][3] = fmaf(av.z, bv.w, a2[2][3]);
            a2[3][0] = fmaf(av.w, bv.x, a2[3][0]);
            a2[3][1] = fmaf(av.w, bv.y, a2[3][1]);
            a2[3][2] = fmaf(av.w, bv.z, a2[3][2]);
            a2[3][3] = fmaf(av.w, bv.w, a2[3][3]);
        }
        const int cb = p * 64 + tx4;
        const float4 bias = *(const float4*)(bb + cb);
#pragma unroll
        for (int i = 0; i < 4; ++i) {
            const int node = n0 + ty4 + i;
            if (node < N_NODES) {
                float4 o;
                o.x = a2[i][0] + bias.x;
                o.y = a2[i][1] + bias.y;
                o.z = a2[i][2] + bias.z;
                o.w = a2[i][3] + bias.w;
                if (TANHF) { o.x = tanhf(o.x); o.y = tanhf(o.y); o.z = tanhf(o.z); o.w = tanhf(o.w); }
                *(float4*)(out + (size_t)node * NOUT + cb) = o;
            }
        }
    }
}

// ---------------------------------------------------------------------------
extern "C" void kernel_launch(void* const* d_in, const int* in_sizes, int n_in,
                              void* d_out, int out_size, void* d_ws, size_t ws_size,
                              hipStream_t stream)
{
    const float* x   = (const float*)d_in[0];
    const int*   ei  = (const int*)  d_in[1];
    const float* ef  = (const float*)d_in[2];
    const float* We1 = (const float*)d_in[3];
    const float* be1 = (const float*)d_in[4];
    const float* W1a = (const float*)d_in[5];
    const float* b1a = (const float*)d_in[6];
    const float* W1b = (const float*)d_in[7];
    const float* b1b = (const float*)d_in[8];
    const float* We2 = (const float*)d_in[9];
    const float* be2 = (const float*)d_in[10];
    const float* W2a = (const float*)d_in[11];
    const float* b2a = (const float*)d_in[12];
    const float* W2b = (const float*)d_in[13];
    const float* b2b = (const float*)d_in[14];
    const float* Wf1 = (const float*)d_in[15];
    const float* bf1 = (const float*)d_in[16];
    const float* Wf2 = (const float*)d_in[17];
    const float* bf2 = (const float*)d_in[18];
    float* out = (float*)d_out;

    const int* src = ei;             // edge_index[0]
    const int* dst = ei + N_EDGES;   // edge_index[1]

    // ---- workspace layout ----
    // persistent through the convs:
    float* agg     = (float*)d_ws;                     // N*128 f (written AFTER sort)
    float* h       = agg + (size_t)N_NODES * 128;      // N*128 f
    int*   row_ptr = (int*)(h + (size_t)N_NODES * 128); // N+1
    int*   perm    = row_ptr + (N_NODES + 1);           // E
    // sort temporaries overlaid on agg (dead once scatter_k completes):
    int* counts    = (int*)agg;                         // N
    int* rank      = counts + N_NODES;                  // E
    int* blockSums = rank + N_EDGES;                    // NB_SCAN
    int* blockOffs = blockSums + NB_SCAN;               // NB_SCAN

    const int mlpGrid = (N_NODES + 63) / 64;
    const int aggGrid = (N_NODES + 1) / 2;
    const int eGrid   = (N_EDGES + 255) / 256;
    const int nGrid   = (N_NODES + 255) / 256;

    // ---- build CSR (same work every call; edge_index is a fixed input) ----
    hipMemsetAsync(counts, 0, (size_t)N_NODES * sizeof(int), stream);
    hist_k   <<<eGrid,   256, 0, stream>>>(dst, counts, rank);
    scan_a_k <<<NB_SCAN, 256, 0, stream>>>(counts, row_ptr, blockSums);
    scan_b_k <<<1,        64, 0, stream>>>(blockSums, blockOffs);
    scan_c_k <<<nGrid,   256, 0, stream>>>(row_ptr, blockOffs);
    scatter_k<<<eGrid,   256, 0, stream>>>(dst, row_ptr, rank, perm);

    // ---- conv1 ----
    agg_csr_k<<<aggGrid, 256, 0, stream>>>(x, src, ef, row_ptr, perm, We1, be1, agg);
    mlp2_k<128, false, true, true><<<mlpGrid, 256, 0, stream>>>(x, agg, W1a, b1a, W1b, b1b, h);

    // ---- conv2 ----
    agg_csr_k<<<aggGrid, 256, 0, stream>>>(h, src, ef, row_ptr, perm, We2, be2, agg);
    mlp2_k<128, false, true, true><<<mlpGrid, 256, 0, stream>>>(h, agg, W2a, b2a, W2b, b2b, h);

    // ---- head ----
    mlp2_k<64, true, false, false><<<mlpGrid, 256, 0, stream>>>(h, nullptr, Wf1, bf1, Wf2, bf2, out);
}